// Round 10
// baseline (93.073 us; speedup 1.0000x reference)
//
#include <hip/hip_runtime.h>
#include <math.h>

#define BB 512
#define DD 128
#define KK 8
#define BOUNDARY 4
#define POISON 0xAAAAAAAAu
#define CELL 128                        // one counter per 128-B line

// ---------------- workspace layout (bytes) ----------------
// partS : 0     .. 2048    (512 float)  per-block partial sum   (agent stores)
// partC : 2048  .. 4096    (512 int)    per-block hinge count   (agent stores)
// cnt1  : 4096  .. 12288   (64 counters, stride 128)  8 blocks each
// cnt2  : 12288 .. 13312   (8 counters, stride 128)   8 shard-winners each
// cnt3  : 13312 .. 13440   (1 counter)                8 super-winners
// ws is re-poisoned 0xAA before every launch. Counters are POISON-TOLERANT:
// arrival index = fetch_add(1) - 0xAAAAAAAA (no CAS, no init). Every counter
// address receives exactly 8 fetch_adds -> per-address serialization <= 8
// (round-8/9 lesson: 512-/64-way same-address returning atomics cost 25-50 us).
// Partials are written unconditionally to distinct slots -> no init, no
// contention; device-scope (agent) stores/loads cross the XCD L2s.
//
// Algebraic facts exploited (boundary = int(512/128) = 4):
//  * anchor rows belong to classes with <= 3 members, so the positive top-8
//    selects ALL same-class rows: mask_ap[i][j] == anchors[i] & tgt[j]==tgt[i] & i!=j.
//  * block k owns column k: its neg top-8 rows r are exactly the (i=r, k)
//    entries of mask_an, and d[r,k] is the value the block just computed.
//  * the <= 16 positive distances d[r,j] per block are recomputed directly
//    from x (one 128-dim dot each) — hinge values only, not selections.

__global__ __launch_bounds__(256) void fused_kernel(
    const float* __restrict__ x, const int* __restrict__ tgt,
    float* __restrict__ partS, int* __restrict__ partC,
    char* __restrict__ cnt1, char* __restrict__ cnt2, char* __restrict__ cnt3,
    float* __restrict__ out)
{
    __shared__ float4 xi4[DD / 4];
    __shared__ float s_d[BB];          // raw distances, column k (== row k)
    __shared__ float s_vn[BB];         // -d masked to -inf on same-class
    __shared__ float s_sq[BB];         // squared norms of all rows
    __shared__ int   s_tgt[BB];
    __shared__ int   s_cnt[128];       // class histogram
    __shared__ int   s_sel[KK];        // selected neg rows, -1 invalid
    __shared__ int   s_pr[16], s_pj[16];
    __shared__ int   s_np;

    int k = blockIdx.x;
    int t = threadIdx.x;
    if (t < DD / 4) xi4[t] = ((const float4*)(x + k * DD))[t];
    if (t < 128) s_cnt[t] = 0;
    if (t == 0) s_np = 0;
    s_tgt[t]       = tgt[t];
    s_tgt[t + 256] = tgt[t + 256];
    __syncthreads();
    int tk = s_tgt[k];

    // sqk with the same 4-chain structure as sqr below -> diagonal exactly 0
    float q0 = 0.f, q1 = 0.f, q2 = 0.f, q3 = 0.f;
    for (int c = 0; c < DD / 4; ++c) {
        float4 a = xi4[c];
        q0 += a.x * a.x; q1 += a.y * a.y; q2 += a.z * a.z; q3 += a.w * a.w;
    }
    float sqk = (q0 + q1) + (q2 + q3);

    for (int rr = 0; rr < 2; ++rr) {
        int r = t + rr * 256;
        const float4* xr = (const float4*)(x + r * DD);
        float d0 = 0.f, d1 = 0.f, d2 = 0.f, d3 = 0.f;
        float s0 = 0.f, s1 = 0.f, s2 = 0.f, s3 = 0.f;
        for (int c = 0; c < DD / 4; ++c) {
            float4 a = xi4[c], b = xr[c];
            d0 += a.x * b.x; d1 += a.y * b.y; d2 += a.z * b.z; d3 += a.w * b.w;
            s0 += b.x * b.x; s1 += b.y * b.y; s2 += b.z * b.z; s3 += b.w * b.w;
        }
        float dot = (d0 + d1) + (d2 + d3);
        float sqr = (s0 + s1) + (s2 + s3);
        float dsq = fmaxf((sqk + sqr) - 2.f * dot, 0.f);
        float dv = (dsq == 0.f) ? 0.f : sqrtf(dsq);
        s_d[r]  = dv;
        s_sq[r] = sqr;
        s_vn[r] = (s_tgt[r] == tk) ? -INFINITY : -dv;
    }
    __syncthreads();

    int wave = t >> 6, lane = t & 63;
    if (wave == 0) {
        // neg top-8: largest -d among different-class rows (lax.top_k order:
        // descending value, lower index on tie) — byte-identical to round 9
        float v[8];
        for (int q = 0; q < 8; ++q) v[q] = s_vn[q * 64 + lane];
        for (int pass = 0; pass < KK; ++pass) {
            float bv = -INFINITY; int bq = -1;
            for (int q = 0; q < 8; ++q)
                if (v[q] > bv) { bv = v[q]; bq = q; }   // strict > keeps lowest q
            int bi = (bq >= 0) ? (bq * 64 + lane) : (1 << 30);
            for (int off = 32; off > 0; off >>= 1) {
                float ov = __shfl_down(bv, off);
                int   oi = __shfl_down(bi, off);
                if (ov > bv || (ov == bv && oi < bi)) { bv = ov; bi = oi; }
            }
            bv = __shfl(bv, 0); bi = __shfl(bi, 0);
            if (lane == 0) s_sel[pass] = (bv == -INFINITY) ? -1 : bi;
            if ((bi & 63) == lane) v[bi >> 6] = -INFINITY;
        }
    } else if (wave == 1) {
        // class histogram (includes self-counts)
        for (int q = 0; q < 8; ++q) atomicAdd(&s_cnt[s_tgt[q * 64 + lane]], 1);
    }
    __syncthreads();

    // collect (anchor r, positive j) pairs: 8 groups of 32 threads, one per slot
    {
        int p = t >> 5, l = t & 31;
        int r = s_sel[p];
        if (r >= 0) {
            int tr = s_tgt[r];
            if (s_cnt[tr] < BOUNDARY) {          // anchor: class size <= 3
                for (int j = l; j < BB; j += 32)
                    if (j != r && s_tgt[j] == tr) {
                        int idx = atomicAdd(&s_np, 1);
                        s_pr[idx] = r; s_pj[idx] = j;
                    }
            }
        }
    }
    __syncthreads();

    // hinge terms: <= 16 pairs, all resident in wave 0
    float s = 0.f; int c = 0;
    if (t < s_np) {
        int r = s_pr[t], j = s_pj[t];
        const float4* xr = (const float4*)(x + r * DD);
        const float4* xj = (const float4*)(x + j * DD);
        float d0 = 0.f, d1 = 0.f, d2 = 0.f, d3 = 0.f;
        for (int cc = 0; cc < DD / 4; ++cc) {
            float4 a = xr[cc], b = xj[cc];
            d0 += a.x * b.x; d1 += a.y * b.y; d2 += a.z * b.z; d3 += a.w * b.w;
        }
        float dot = (d0 + d1) + (d2 + d3);
        float dsq = fmaxf((s_sq[r] + s_sq[j]) - 2.f * dot, 0.f);
        float dpos = (dsq == 0.f) ? 0.f : sqrtf(dsq);
        float tv = dpos - s_d[r] + 1.0f;         // d[r,j] - d[r,k] + margin
        if (tv > 0.f) { s = tv; c = (tv > 1e-7f) ? 1 : 0; }
    }

    if (wave == 0) {
        for (int off = 32; off > 0; off >>= 1) {
            s += __shfl_down(s, off);
            c += __shfl_down(c, off);
        }
        int isFinal = 0;
        if (lane == 0) {
            // publish this block's partial (distinct slots, device scope)
            __hip_atomic_store(&partS[k], s, __ATOMIC_RELAXED, __HIP_MEMORY_SCOPE_AGENT);
            __hip_atomic_store(&partC[k], c, __ATOMIC_RELAXED, __HIP_MEMORY_SCOPE_AGENT);
            // 3-level arrive tree; counters are poison-based (arrival = old - POISON)
            unsigned* c1 = (unsigned*)(cnt1 + (size_t)(k >> 3) * CELL);
            unsigned o1 = __hip_atomic_fetch_add(c1, 1u, __ATOMIC_ACQ_REL, __HIP_MEMORY_SCOPE_AGENT);
            if (o1 - POISON == 7u) {
                unsigned* c2 = (unsigned*)(cnt2 + (size_t)(k >> 6) * CELL);
                unsigned o2 = __hip_atomic_fetch_add(c2, 1u, __ATOMIC_ACQ_REL, __HIP_MEMORY_SCOPE_AGENT);
                if (o2 - POISON == 7u) {
                    unsigned* c3 = (unsigned*)cnt3;
                    unsigned o3 = __hip_atomic_fetch_add(c3, 1u, __ATOMIC_ACQ_REL, __HIP_MEMORY_SCOPE_AGENT);
                    if (o3 - POISON == 7u) isFinal = 1;   // grid-last
                }
            }
        }
        isFinal = __shfl(isFinal, 0);
        if (isFinal) {                 // all publishes happen-before via the tree
            __threadfence();           // acquire (belt & braces)
            float S = 0.f; int C = 0;
            for (int q = 0; q < 8; ++q) {
                int idx = lane * 8 + q;
                S += __hip_atomic_load(&partS[idx], __ATOMIC_RELAXED, __HIP_MEMORY_SCOPE_AGENT);
                C += __hip_atomic_load(&partC[idx], __ATOMIC_RELAXED, __HIP_MEMORY_SCOPE_AGENT);
            }
            for (int off = 32; off > 0; off >>= 1) {
                S += __shfl_down(S, off);
                C += __shfl_down(C, off);
            }
            if (lane == 0) out[0] = S / ((float)C + 1e-7f);
        }
    }
}

extern "C" void kernel_launch(void* const* d_in, const int* in_sizes, int n_in,
                              void* d_out, int out_size, void* d_ws, size_t ws_size,
                              hipStream_t stream) {
    const float* x   = (const float*)d_in[0];
    const int*   tgt = (const int*)d_in[1];
    float* out = (float*)d_out;

    char* ws = (char*)d_ws;
    float* partS = (float*)(ws + 0);
    int*   partC = (int*)(ws + 2048);
    char*  cnt1  = ws + 4096;
    char*  cnt2  = ws + 12288;
    char*  cnt3  = ws + 13312;

    fused_kernel<<<BB, 256, 0, stream>>>(x, tgt, partS, partC, cnt1, cnt2, cnt3, out);
}

// Round 11
// 73.940 us; speedup vs baseline: 1.2588x; 1.2588x over previous
//
#include <hip/hip_runtime.h>
#include <math.h>

#define BB 512
#define DD 128
#define KK 8
#define BOUNDARY 4

// ---------------- workspace layout (bytes) ----------------
// partS : 0    .. 2048   (512 float)  per-block loss partial sum
// partC : 2048 .. 4096   (512 int)    per-block hinge count
// Written unconditionally by every block -> no memset needed.
// NO device-scope atomics/fences anywhere: rounds 8-10 showed any
// single-kernel finalize (contended atomics or acq_rel trees) costs
// 40-60 us of cross-XCD coherence tail; a second tiny dispatch is cheaper.
//
// Algebraic facts exploited (boundary = int(512/128) = 4):
//  * anchor rows belong to classes with <= 3 members, so the positive top-8
//    selects ALL same-class rows: mask_ap[i][j] == anchors[i] & tgt[j]==tgt[i] & i!=j.
//  * block k owns column k: its neg top-8 rows r are exactly the (i=r, k)
//    entries of mask_an, and d[r,k] = -s_vn[r] (selected negs are always
//    different-class, where s_vn holds -d).
//  * the diagonal d[k,k] is never consumed (neg-masked; positives exclude
//    j==r), so no exact-zero trick is needed.
//  * the <= 16 positive distances d[r,j] per block are recomputed directly
//    from x (one 128-dim dot each) — hinge values only, not selections.

__global__ __launch_bounds__(256) void fused_kernel(
    const float* __restrict__ x, const int* __restrict__ tgt,
    float* __restrict__ partS, int* __restrict__ partC)
{
    __shared__ float4 xi4[DD / 4];
    __shared__ float s_vn[BB];         // -d, masked to -inf on same-class
    __shared__ float s_sq[BB];         // squared norms of all rows
    __shared__ int   s_tgt[BB];
    __shared__ int   s_cnt[128];       // class histogram
    __shared__ int   s_sel[KK];        // selected neg rows, -1 invalid
    __shared__ int   s_pr[16], s_pj[16];
    __shared__ int   s_np;

    int k = blockIdx.x;
    int t = threadIdx.x;
    if (t < DD / 4) xi4[t] = ((const float4*)(x + k * DD))[t];
    if (t < 128) s_cnt[t] = 0;
    if (t == 0) s_np = 0;
    s_tgt[t]       = tgt[t];
    s_tgt[t + 256] = tgt[t + 256];
    __syncthreads();
    int tk = s_tgt[k];

    float q0 = 0.f, q1 = 0.f, q2 = 0.f, q3 = 0.f;
    for (int c = 0; c < DD / 4; ++c) {
        float4 a = xi4[c];
        q0 += a.x * a.x; q1 += a.y * a.y; q2 += a.z * a.z; q3 += a.w * a.w;
    }
    float sqk = (q0 + q1) + (q2 + q3);

    // distance loop: 8 lanes cooperate per row (coalesced 128-B segments).
    // thread t: row-group g = t>>3 (0..31), sub-lane sub = t&7.
    // 16 passes x 32 groups cover 512 rows; sub reads chunks sub+8c, c=0..3.
    {
        int g = t >> 3, sub = t & 7;
        for (int pass = 0; pass < 16; ++pass) {
            int r = pass * 32 + g;
            const float4* xr = (const float4*)(x + r * DD);
            float d0 = 0.f, d1 = 0.f, d2 = 0.f, d3 = 0.f;   // dot, 4 indep chains
            float s0 = 0.f, s1 = 0.f, s2 = 0.f, s3 = 0.f;   // sq
            {
                float4 a = xi4[sub],      b = xr[sub];
                d0 = a.x*b.x + a.y*b.y + a.z*b.z + a.w*b.w;
                s0 = b.x*b.x + b.y*b.y + b.z*b.z + b.w*b.w;
            }
            {
                float4 a = xi4[sub + 8],  b = xr[sub + 8];
                d1 = a.x*b.x + a.y*b.y + a.z*b.z + a.w*b.w;
                s1 = b.x*b.x + b.y*b.y + b.z*b.z + b.w*b.w;
            }
            {
                float4 a = xi4[sub + 16], b = xr[sub + 16];
                d2 = a.x*b.x + a.y*b.y + a.z*b.z + a.w*b.w;
                s2 = b.x*b.x + b.y*b.y + b.z*b.z + b.w*b.w;
            }
            {
                float4 a = xi4[sub + 24], b = xr[sub + 24];
                d3 = a.x*b.x + a.y*b.y + a.z*b.z + a.w*b.w;
                s3 = b.x*b.x + b.y*b.y + b.z*b.z + b.w*b.w;
            }
            float dot = (d0 + d1) + (d2 + d3);
            float sq  = (s0 + s1) + (s2 + s3);
            // reduce over the 8 sub-lanes (lanes g*8 .. g*8+7 of the wave)
            for (int off = 4; off > 0; off >>= 1) {
                dot += __shfl_down(dot, off, 8);
                sq  += __shfl_down(sq,  off, 8);
            }
            if (sub == 0) {
                float dsq = fmaxf((sqk + sq) - 2.f * dot, 0.f);
                float dv = (dsq == 0.f) ? 0.f : sqrtf(dsq);
                s_sq[r] = sq;
                s_vn[r] = (s_tgt[r] == tk) ? -INFINITY : -dv;
            }
        }
    }
    __syncthreads();

    int wave = t >> 6, lane = t & 63;
    if (wave == 0) {
        // neg top-8: largest -d among different-class rows (lax.top_k order:
        // descending value, lower index on tie)
        float v[8];
        for (int q = 0; q < 8; ++q) v[q] = s_vn[q * 64 + lane];
        for (int pass = 0; pass < KK; ++pass) {
            float bv = -INFINITY; int bq = -1;
            for (int q = 0; q < 8; ++q)
                if (v[q] > bv) { bv = v[q]; bq = q; }   // strict > keeps lowest q
            int bi = (bq >= 0) ? (bq * 64 + lane) : (1 << 30);
            for (int off = 32; off > 0; off >>= 1) {
                float ov = __shfl_down(bv, off);
                int   oi = __shfl_down(bi, off);
                if (ov > bv || (ov == bv && oi < bi)) { bv = ov; bi = oi; }
            }
            bv = __shfl(bv, 0); bi = __shfl(bi, 0);
            if (lane == 0) s_sel[pass] = (bv == -INFINITY) ? -1 : bi;
            if ((bi & 63) == lane) v[bi >> 6] = -INFINITY;
        }
    } else if (wave == 1) {
        // class histogram (includes self-counts)
        for (int q = 0; q < 8; ++q) atomicAdd(&s_cnt[s_tgt[q * 64 + lane]], 1);
    }
    __syncthreads();

    // collect (anchor r, positive j) pairs: 8 groups of 32 threads, one per slot
    {
        int p = t >> 5, l = t & 31;
        int r = s_sel[p];
        if (r >= 0) {
            int tr = s_tgt[r];
            if (s_cnt[tr] < BOUNDARY) {          // anchor: class size <= 3
                for (int j = l; j < BB; j += 32)
                    if (j != r && s_tgt[j] == tr) {
                        int idx = atomicAdd(&s_np, 1);
                        s_pr[idx] = r; s_pj[idx] = j;
                    }
            }
        }
    }
    __syncthreads();

    // hinge terms: <= 16 pairs, all resident in wave 0
    float s = 0.f; int c = 0;
    if (t < s_np) {
        int r = s_pr[t], j = s_pj[t];
        const float4* xr = (const float4*)(x + r * DD);
        const float4* xj = (const float4*)(x + j * DD);
        float d0 = 0.f, d1 = 0.f, d2 = 0.f, d3 = 0.f;
        for (int cc = 0; cc < DD / 4; ++cc) {
            float4 a = xr[cc], b = xj[cc];
            d0 += a.x * b.x; d1 += a.y * b.y; d2 += a.z * b.z; d3 += a.w * b.w;
        }
        float dot = (d0 + d1) + (d2 + d3);
        float dsq = fmaxf((s_sq[r] + s_sq[j]) - 2.f * dot, 0.f);
        float dpos = (dsq == 0.f) ? 0.f : sqrtf(dsq);
        float tv = dpos + s_vn[r] + 1.0f;        // d[r,j] - d[r,k] + margin
        if (tv > 0.f) { s = tv; c = (tv > 1e-7f) ? 1 : 0; }
    }
    if (wave == 0) {
        for (int off = 32; off > 0; off >>= 1) {
            s += __shfl_down(s, off);
            c += __shfl_down(c, off);
        }
        if (lane == 0) { partS[k] = s; partC[k] = c; }
    }
}

__global__ __launch_bounds__(64) void fin_kernel(
    const float* __restrict__ partS, const int* __restrict__ partC,
    float* __restrict__ out)
{
    int lane = threadIdx.x;              // 0..63
    const float4* pS = (const float4*)partS;
    const int4*   pC = (const int4*)partC;
    float4 a = pS[lane], b = pS[lane + 64];
    int4   u = pC[lane], v = pC[lane + 64];
    float S = ((a.x + a.y) + (a.z + a.w)) + ((b.x + b.y) + (b.z + b.w));
    int   C = ((u.x + u.y) + (u.z + u.w)) + ((v.x + v.y) + (v.z + v.w));
    for (int off = 32; off > 0; off >>= 1) {
        S += __shfl_down(S, off);
        C += __shfl_down(C, off);
    }
    if (lane == 0) out[0] = S / ((float)C + 1e-7f);
}

extern "C" void kernel_launch(void* const* d_in, const int* in_sizes, int n_in,
                              void* d_out, int out_size, void* d_ws, size_t ws_size,
                              hipStream_t stream) {
    const float* x   = (const float*)d_in[0];
    const int*   tgt = (const int*)d_in[1];
    float* out = (float*)d_out;

    char* ws = (char*)d_ws;
    float* partS = (float*)(ws + 0);
    int*   partC = (int*)(ws + 2048);

    fused_kernel<<<BB, 256, 0, stream>>>(x, tgt, partS, partC);
    fin_kernel<<<1, 64, 0, stream>>>(partS, partC, out);
}